// Round 18
// baseline (376.367 us; speedup 1.0000x reference)
//
#include <hip/hip_runtime.h>

// LinearCrossAttention: B=8, N=T=4096, C=512, H=8, d=64, 3 terms.
// R18: q-GEMM and y-cvt interleaved by (blockIdx.x & 1) in one launch
// (true MFMA/BW overlap — z-ordered merge ran them serially). kvctx back
// to standalone launch. combine2/reduce/final unchanged from R17.

#define B_  8
#define N_  4096
#define C_  512
#define T_  4096
#define H_  8
#define M_  (B_*N_)   // 32768

typedef __bf16 bf16_8 __attribute__((ext_vector_type(8)));
typedef __bf16 bf16_4 __attribute__((ext_vector_type(4)));
typedef float  f32_4  __attribute__((ext_vector_type(4)));

__device__ __forceinline__ unsigned short f2bf(float f) {
  unsigned u = __float_as_uint(f);
  unsigned r = 0x7FFFu + ((u >> 16) & 1u);
  return (unsigned short)((u + r) >> 16);
}
__device__ __forceinline__ unsigned pack2(float lo, float hi) {
  return (unsigned)f2bf(lo) | ((unsigned)f2bf(hi) << 16);
}

__device__ __forceinline__ void gload16(const void* g, void* l) {
  __builtin_amdgcn_global_load_lds(
      (const __attribute__((address_space(1))) unsigned int*)g,
      (__attribute__((address_space(3))) unsigned int*)l, 16, 0, 0);
}

__device__ __forceinline__ bf16_8 cvt8(float4 a, float4 b) {
  bf16_8 v;
  v[0]=(__bf16)a.x; v[1]=(__bf16)a.y; v[2]=(__bf16)a.z; v[3]=(__bf16)a.w;
  v[4]=(__bf16)b.x; v[5]=(__bf16)b.y; v[6]=(__bf16)b.z; v[7]=(__bf16)b.w;
  return v;
}

// ---------------- weight conversions (one small launch) ---------------------
__global__ __launch_bounds__(256) void cvt_weights(
    const float* __restrict__ Wq, const float* __restrict__ Wk,
    const float* __restrict__ Wv, const float* __restrict__ Wp,
    unsigned short* __restrict__ wb)   // [8*C*C] : Wq | Wk(3) | Wv(3) | Wp
{
  const size_t WCC = (size_t)C_*C_;
  const float* src; unsigned short* dst; long n4;
  switch (blockIdx.y) {
    case 0: src = Wq; dst = wb;         n4 = WCC/4;   break;
    case 1: src = Wk; dst = wb + WCC;   n4 = 3*WCC/4; break;
    case 2: src = Wv; dst = wb + 4*WCC; n4 = 3*WCC/4; break;
    default:src = Wp; dst = wb + 7*WCC; n4 = WCC/4;   break;
  }
  long i = (long)blockIdx.x * blockDim.x + threadIdx.x;
  long stride = (long)gridDim.x * blockDim.x;
  for (; i < n4; i += stride) {
    float4 v = ((const float4*)src)[i];
    ushort4 o;
    o.x = f2bf(v.x); o.y = f2bf(v.y); o.z = f2bf(v.z); o.w = f2bf(v.w);
    ((ushort4*)dst)[i] = o;
  }
}

// ---------------- q-GEMM + y-cvt, role interleaved by x&1 -------------------
// grid (2048): odd blocks = y-cvt slice, even blocks = q-gemm tile.
__global__ __launch_bounds__(256, 2) void qcvt_kernel(
    const float* __restrict__ xf,
    const unsigned short* __restrict__ wq_b, const float* __restrict__ bq,
    unsigned short* __restrict__ qb,
    const float* __restrict__ y, unsigned short* __restrict__ yb)
{
  __shared__ char smem[65536];
  const int tid = threadIdx.x, lane = tid & 63, wid = tid >> 6;
  const int wr = wid >> 1, wc = wid & 1;
  const int l15 = lane & 15, l16 = lane >> 4;
  const int flat = blockIdx.x;

  if (flat & 1) {
    // ---- y-cvt role: slice (flat>>1) of 1024, 32B/lane ----
    const long n8 = (long)3*M_*C_/8;       // 6.29M units of 8 floats
    const long per = n8 / 1024;            // 6144 (exact)
    const long beg = (long)(flat >> 1) * per;
    for (long i = beg + tid; i < beg + per; i += 256) {
      float4 a = ((const float4*)y)[2*i];
      float4 b = ((const float4*)y)[2*i + 1];
      uint4 o;
      o.x = pack2(a.x, a.y); o.y = pack2(a.z, a.w);
      o.z = pack2(b.x, b.y); o.w = pack2(b.z, b.w);
      ((uint4*)yb)[i] = o;
    }
    return;
  }

  // ---- q-GEMM role: qb = softmax(x @ Wq^T + bq), A = x f32 ----
  const int qidx = flat >> 1;              // 0..1023
  const size_t row0 = (size_t)(qidx & 255) * 128;
  const int col0 = (qidx >> 8) * 128;

  f32_4 acc[4][4] = {};
  float4 ra[4][2];

  auto load_a = [&](int k0) {
#pragma unroll
    for (int j = 0; j < 4; ++j) {
      int cc = j*256 + tid, row = cc >> 3, s = cc & 7;
      const float* src = xf + (row0 + row)*512 + k0 + s*8;
      ra[j][0] = *(const float4*)src;
      ra[j][1] = *(const float4*)(src + 4);
    }
  };
  auto write_a = [&](int bsel) {
    unsigned short* dst = (unsigned short*)smem;
#pragma unroll
    for (int j = 0; j < 4; ++j) {
      int cc = j*256 + tid, row = cc >> 3, s = cc & 7;
      *(bf16_8*)&dst[bsel*8192 + row*64 + ((s ^ (row & 7)) << 3)] = cvt8(ra[j][0], ra[j][1]);
    }
  };
  auto stage_b = [&](int k0, int bsel) {
#pragma unroll
    for (int j = 0; j < 4; ++j) {
      int cc = j*256 + tid, row = cc >> 3, s = cc & 7;
      gload16(wq_b + (size_t)(col0 + row)*512 + k0 + ((s ^ (row & 7)) << 3),
              smem + 32768 + bsel*16384 + (size_t)(j*256 + wid*64)*16);
    }
  };

  load_a(0); stage_b(0, 0); write_a(0);
  __syncthreads();
  for (int t = 0; t < 8; ++t) {
    int cur = t & 1;
    if (t < 7) { load_a((t+1)*64); stage_b((t+1)*64, cur ^ 1); }
    const unsigned short* sA = (const unsigned short*)(smem + cur*16384);
    const unsigned short* sB = (const unsigned short*)(smem + 32768 + cur*16384);
#pragma unroll
    for (int kk = 0; kk < 64; kk += 32) {
      bf16_8 af[4], bfr[4];
#pragma unroll
      for (int mi = 0; mi < 4; ++mi) {
        int r = wr*64 + mi*16 + l15;
        int ch = (kk >> 3) + l16;
        af[mi] = *(const bf16_8*)&sA[r*64 + ((ch ^ (r & 7)) << 3)];
      }
#pragma unroll
      for (int ni = 0; ni < 4; ++ni) {
        int r = wc*64 + ni*16 + l15;
        int ch = (kk >> 3) + l16;
        bfr[ni] = *(const bf16_8*)&sB[r*64 + ((ch ^ (r & 7)) << 3)];
      }
#pragma unroll
      for (int mi = 0; mi < 4; ++mi)
#pragma unroll
        for (int ni = 0; ni < 4; ++ni)
          acc[mi][ni] = __builtin_amdgcn_mfma_f32_16x16x32_bf16(af[mi], bfr[ni], acc[mi][ni], 0, 0, 0);
    }
    if (t < 7) write_a(cur ^ 1);
    __syncthreads();
  }

  float bvv[4];
#pragma unroll
  for (int ni = 0; ni < 4; ++ni) bvv[ni] = bq[col0 + wc*64 + ni*16 + l15];
  unsigned short* sE = (unsigned short*)smem;   // 128 x pitch 136
#pragma unroll
  for (int mi = 0; mi < 4; ++mi) {
#pragma unroll
    for (int jj = 0; jj < 4; ++jj) {
      float x[4];
      float s = 0.f;
#pragma unroll
      for (int ni = 0; ni < 4; ++ni) {
        x[ni] = __expf(acc[mi][ni][jj] + bvv[ni]);   // bounded: no max-sub
        s += x[ni];
      }
#pragma unroll
      for (int o = 8; o; o >>= 1) s += __shfl_xor(s, o);
      float inv = 1.0f / s;
      int r = wr*64 + mi*16 + l16*4 + jj;
#pragma unroll
      for (int ni = 0; ni < 4; ++ni) {
        __bf16 h = (__bf16)(x[ni] * inv);
        sE[r*136 + wc*64 + ni*16 + l15] = *(unsigned short*)&h;
      }
    }
  }
  __syncthreads();
  int r = tid >> 1, seg = tid & 1;
  unsigned short* orow = qb + (row0 + r)*512 + col0 + seg*64;
#pragma unroll
  for (int u = 0; u < 8; ++u)
    *(uint4*)(orow + u*8) = *(const uint4*)&sE[r*136 + seg*64 + u*8];
}

// ---------------- fused K/V GEMM + softmax + ctx/kc partials ----------------
// grid (512, 1, 3): x = h*64 + bx (same-bx blocks share one XCD & y slab).
__global__ __launch_bounds__(256, 2) void kvctx_kernel(
    const unsigned short* __restrict__ yb_all,
    const unsigned short* __restrict__ wk_all,
    const unsigned short* __restrict__ wv_all,
    const float* __restrict__ bk_all, const float* __restrict__ bv_all,
    float* __restrict__ part, float* __restrict__ kcp)
{
  __shared__ char smem[65536];
  unsigned short* sKT = (unsigned short*)smem;             // 64*136*2 = 17408
  unsigned short* sVT = (unsigned short*)(smem + 17408);

  const int tid = threadIdx.x, lane = tid & 63, wid = tid >> 6;
  const int wr = wid >> 1, wc = wid & 1;
  const int l15 = lane & 15, l16 = lane >> 4;
  const int gx = blockIdx.x, i = blockIdx.z;
  const int h = gx >> 6, bx = gx & 63;
  const int b = bx >> 3, sub = bx & 7;
  const int bh = b*8 + h;

  const unsigned short* yb = yb_all + (size_t)i*M_*512;
  const unsigned short* Wk_b = wk_all + (size_t)i*512*512 + (size_t)h*64*512;
  const unsigned short* Wv_b = wv_all + (size_t)i*512*512 + (size_t)h*64*512;
  const float* bk = bk_all + i*512 + h*64;
  const float* bv = bv_all + i*512 + h*64;

  f32_4 cacc[2][2] = {};
  float kcp_r[4] = {0.f, 0.f, 0.f, 0.f};

  for (int chunk = 0; chunk < 4; ++chunk) {
    const size_t row0 = (size_t)bx*512 + chunk*128;
    f32_4 acc[4][4] = {};

    auto stage = [&](int k0, int bsel) {
#pragma unroll
      for (int j = 0; j < 4; ++j) {
        int cc = j*256 + tid, row = cc >> 3, s = cc & 7;
        gload16(yb + (row0 + row)*512 + k0 + ((s ^ (row & 7)) << 3),
                smem + bsel*16384 + (size_t)(j*256 + wid*64)*16);
        const unsigned short* wsrc = (j < 2)
            ? Wk_b + (size_t)row*512
            : Wv_b + (size_t)(row - 64)*512;
        gload16(wsrc + k0 + ((s ^ (row & 7)) << 3),
                smem + 32768 + bsel*16384 + (size_t)(j*256 + wid*64)*16);
      }
    };

    stage(0, 0);
    __syncthreads();
    for (int t = 0; t < 8; ++t) {
      int cur = t & 1;
      if (t < 7) stage((t+1)*64, cur ^ 1);
      const unsigned short* sA = (const unsigned short*)(smem + cur*16384);
      const unsigned short* sB = (const unsigned short*)(smem + 32768 + cur*16384);
#pragma unroll
      for (int kk = 0; kk < 64; kk += 32) {
        bf16_8 af[4], bfr[4];
#pragma unroll
        for (int mi = 0; mi < 4; ++mi) {
          int r = wr*64 + mi*16 + l15;
          int ch = (kk >> 3) + l16;
          af[mi] = *(const bf16_8*)&sA[r*64 + ((ch ^ (r & 7)) << 3)];
        }
#pragma unroll
        for (int ni = 0; ni < 4; ++ni) {
          int r = wc*64 + ni*16 + l15;
          int ch = (kk >> 3) + l16;
          bfr[ni] = *(const bf16_8*)&sB[r*64 + ((ch ^ (r & 7)) << 3)];
        }
#pragma unroll
        for (int mi = 0; mi < 4; ++mi)
#pragma unroll
          for (int ni = 0; ni < 4; ++ni)
            acc[mi][ni] = __builtin_amdgcn_mfma_f32_16x16x32_bf16(af[mi], bfr[ni], acc[mi][ni], 0, 0, 0);
      }
      __syncthreads();
    }

    if (wc == 0) {
      float bkv[4];
#pragma unroll
      for (int ni = 0; ni < 4; ++ni) bkv[ni] = bk[ni*16 + l15];
#pragma unroll
      for (int mi = 0; mi < 4; ++mi) {
        float kv[4][4];
#pragma unroll
        for (int jj = 0; jj < 4; ++jj) {
          float s = 0.f;
#pragma unroll
          for (int ni = 0; ni < 4; ++ni) {
            kv[jj][ni] = __expf(acc[mi][ni][jj] + bkv[ni]);
            s += kv[jj][ni];
          }
#pragma unroll
          for (int o = 8; o; o >>= 1) s += __shfl_xor(s, o);
          float inv = 1.0f / s;
#pragma unroll
          for (int ni = 0; ni < 4; ++ni) kv[jj][ni] *= inv;
        }
        int r0 = wr*64 + mi*16 + l16*4;
#pragma unroll
        for (int ni = 0; ni < 4; ++ni) {
          kcp_r[ni] += (kv[0][ni] + kv[1][ni]) + (kv[2][ni] + kv[3][ni]);
          bf16_4 p;
#pragma unroll
          for (int jj = 0; jj < 4; ++jj) p[jj] = (__bf16)kv[jj][ni];
          *(bf16_4*)&sKT[(ni*16 + l15)*136 + r0] = p;
        }
      }
    } else {
      float bvv[4];
#pragma unroll
      for (int ni = 0; ni < 4; ++ni) bvv[ni] = bv[ni*16 + l15];
#pragma unroll
      for (int mi = 0; mi < 4; ++mi) {
        int r0 = wr*64 + mi*16 + l16*4;
#pragma unroll
        for (int ni = 0; ni < 4; ++ni) {
          bf16_4 p;
#pragma unroll
          for (int jj = 0; jj < 4; ++jj) p[jj] = (__bf16)(acc[mi][ni][jj] + bvv[ni]);
          *(bf16_4*)&sVT[(ni*16 + l15)*136 + r0] = p;
        }
      }
    }
    __syncthreads();

#pragma unroll
    for (int ks = 0; ks < 4; ++ks) {
      bf16_8 a2[2], b2[2];
#pragma unroll
      for (int mi = 0; mi < 2; ++mi)
        a2[mi] = *(const bf16_8*)&sKT[(wr*32 + mi*16 + l15)*136 + ks*32 + l16*8];
#pragma unroll
      for (int ni = 0; ni < 2; ++ni)
        b2[ni] = *(const bf16_8*)&sVT[(wc*32 + ni*16 + l15)*136 + ks*32 + l16*8];
#pragma unroll
      for (int mi = 0; mi < 2; ++mi)
#pragma unroll
        for (int ni = 0; ni < 2; ++ni)
          cacc[mi][ni] = __builtin_amdgcn_mfma_f32_16x16x32_bf16(a2[mi], b2[ni], cacc[mi][ni], 0, 0, 0);
    }
    __syncthreads();
  }

  const size_t slot = (size_t)(i*64 + bh)*8 + sub;
  if (wc == 0) {
#pragma unroll
    for (int ni = 0; ni < 4; ++ni) {
      float s = kcp_r[ni];
      s += __shfl_xor(s, 16);
      s += __shfl_xor(s, 32);
      if (l16 == 0) kcp[(slot*2 + wr)*64 + ni*16 + l15] = s;
    }
  }
  float* pb = part + slot*4096;
#pragma unroll
  for (int mi = 0; mi < 2; ++mi)
#pragma unroll
    for (int ni = 0; ni < 2; ++ni) {
      int e0 = wr*32 + mi*16 + l16*4;
      int dv = wc*32 + ni*16 + l15;
      *(f32_4*)&pb[dv*64 + e0] = cacc[mi][ni];
    }
}

// ---------------- reduce partials -> ctxT, kc -------------------------------
__global__ __launch_bounds__(256) void ctx_reduce(
    const float* __restrict__ part,   // [192][8][4096]
    const float* __restrict__ kcp,    // [192][8][2][64]
    float* __restrict__ ctxT,         // [192][4096]
    float* __restrict__ kc)           // [192][64]
{
  int g = blockIdx.x;
  const float* p = part + (size_t)g*8*4096;
  float* o = ctxT + (size_t)g*4096;
#pragma unroll
  for (int jj = 0; jj < 4; ++jj) {
    int j = (jj*256 + threadIdx.x)*4;
    f32_4 s = {};
#pragma unroll
    for (int r = 0; r < 8; ++r) {
      f32_4 v = *(const f32_4*)&p[(size_t)r*4096 + j];
      s[0] += v[0]; s[1] += v[1]; s[2] += v[2]; s[3] += v[3];
    }
    *(f32_4*)&o[j] = s;
  }
  if (threadIdx.x < 64) {
    const float* pk = kcp + (size_t)g*16*64;
    float s = 0.f;
#pragma unroll
    for (int r = 0; r < 16; ++r) s += pk[r*64 + threadIdx.x];
    kc[(size_t)g*64 + threadIdx.x] = s;
  }
}

// ---------------- combine (MFMA): out = q + sum_i (q@ctx_i)/(q.kc_i) --------
__global__ __launch_bounds__(256) void combine2(
    const unsigned short* __restrict__ qb,
    const float* __restrict__ ctxT,          // [3][64bh][64dv][64e]
    const float* __restrict__ kc,            // [3][64bh][64e]
    unsigned short* __restrict__ outp)
{
  __shared__ unsigned short sQ[128*64];
  __shared__ unsigned short sB[208*72];
  __shared__ float sS[128*3];
  const int tid = threadIdx.x, lane = tid & 63, wid = tid >> 6;
  const int l15 = lane & 15, l16 = lane >> 4;
  const int bh = blockIdx.y, b = bh >> 3, h = bh & 7;
  const int n0 = blockIdx.x * 128;
  const size_t qbase = ((size_t)b*N_ + n0)*C_ + h*64;

#pragma unroll
  for (int j = 0; j < 4; ++j) {
    int c = j*256 + tid;
    int row = c >> 3, c8 = c & 7;
    gload16(qb + qbase + (size_t)row*C_ + ((c8 ^ (row & 7)) << 3),
            sQ + (size_t)(j*256 + wid*64)*8);
  }
  for (int f = tid; f < 208*64; f += 256) {
    int col = f >> 6, e = f & 63;
    float val = 0.f;
    if (col < 192)
      val = ctxT[(((size_t)(col >> 6)*64 + bh)*64 + (col & 63))*64 + e];
    else if (col < 195)
      val = kc[((size_t)(col - 192)*64 + bh)*64 + e];
    __bf16 hv = (__bf16)val;
    sB[col*72 + e] = *(unsigned short*)&hv;
  }
  __syncthreads();

  f32_4 acc[2][13] = {};
#pragma unroll
  for (int ks = 0; ks < 2; ++ks) {
    bf16_8 af[2];
#pragma unroll
    for (int mi = 0; mi < 2; ++mi) {
      int r = wid*32 + mi*16 + l15;
      int ch = ks*4 + l16;
      af[mi] = *(const bf16_8*)&sQ[r*64 + ((ch ^ (r & 7)) << 3)];
    }
#pragma unroll
    for (int ni = 0; ni < 13; ++ni) {
      bf16_8 bfr = *(const bf16_8*)&sB[(ni*16 + l15)*72 + ks*32 + l16*8];
#pragma unroll
      for (int mi = 0; mi < 2; ++mi)
        acc[mi][ni] = __builtin_amdgcn_mfma_f32_16x16x32_bf16(af[mi], bfr, acc[mi][ni], 0, 0, 0);
    }
  }

  if (l15 < 3) {
#pragma unroll
    for (int mi = 0; mi < 2; ++mi)
#pragma unroll
      for (int jj = 0; jj < 4; ++jj)
        sS[(wid*32 + mi*16 + l16*4 + jj)*3 + l15] = acc[mi][12][jj];
  }
  __syncthreads();

#pragma unroll
  for (int mi = 0; mi < 2; ++mi) {
#pragma unroll
    for (int jj = 0; jj < 4; ++jj) {
      int r = wid*32 + mi*16 + l16*4 + jj;
      float inv[3];
#pragma unroll
      for (int i = 0; i < 3; ++i) inv[i] = 1.0f / sS[r*3 + i];
#pragma unroll
      for (int ni = 0; ni < 4; ++ni) {
        int dv = ni*16 + l15;
        unsigned short qh = sQ[r*64 + ((((dv >> 3) ^ (r & 7))) << 3) + (dv & 7)];
        float val = __uint_as_float(((unsigned)qh) << 16);
#pragma unroll
        for (int i = 0; i < 3; ++i) val += acc[mi][i*4 + ni][jj] * inv[i];
        __bf16 hv = (__bf16)val;
        outp[qbase + (size_t)r*C_ + dv] = *(unsigned short*)&hv;
      }
    }
  }
}

// ---------------- final GEMM (bf16 A), 128x128, BK=64 dbuf ------------------
__global__ __launch_bounds__(256, 2) void gemm_final(
    const unsigned short* __restrict__ A,
    const unsigned short* __restrict__ Bw,
    const float* __restrict__ bias,
    float* __restrict__ Cf)
{
  __shared__ char smem[65536];
  const int tid = threadIdx.x, lane = tid & 63, wid = tid >> 6;
  const int wr = wid >> 1, wc = wid & 1;
  const int l15 = lane & 15, l16 = lane >> 4;
  const size_t row0 = (size_t)blockIdx.x * 128;
  const int col0 = blockIdx.y * 128;

  f32_4 acc[4][4] = {};

  auto stage = [&](int k0, int bsel) {
#pragma unroll
    for (int j = 0; j < 4; ++j) {
      int cc = j*256 + tid, row = cc >> 3, s = cc & 7;
      gload16(A + (row0 + row)*512 + k0 + ((s ^ (row & 7)) << 3),
              smem + bsel*16384 + (size_t)(j*256 + wid*64)*16);
      gload16(Bw + (size_t)(col0 + row)*512 + k0 + ((s ^ (row & 7)) << 3),
              smem + 32768 + bsel*16384 + (size_t)(j*256 + wid*64)*16);
    }
  };

  stage(0, 0);
  __syncthreads();
  for (int t = 0; t < 8; ++t) {
    int cur = t & 1;
    if (t < 7) stage((t+1)*64, cur ^ 1);
    const unsigned short* sA = (const unsigned short*)(smem + cur*16384);
    const unsigned short* sB = (const unsigned short*)(smem + 32768 + cur*16384);
#pragma unroll
    for (int kk = 0; kk < 64; kk += 32) {
      bf16_8 af[4], bfr[4];
#pragma unroll
      for (int mi = 0; mi < 4; ++mi) {
        int r = wr*64 + mi*16 + l15;
        int ch = (kk >> 3) + l16;
        af[mi] = *(const bf16_8*)&sA[r*64 + ((ch ^ (r & 7)) << 3)];
      }
#pragma unroll
      for (int ni = 0; ni < 4; ++ni) {
        int r = wc*64 + ni*16 + l15;
        int ch = (kk >> 3) + l16;
        bfr[ni] = *(const bf16_8*)&sB[r*64 + ((ch ^ (r & 7)) << 3)];
      }
#pragma unroll
      for (int mi = 0; mi < 4; ++mi)
#pragma unroll
        for (int ni = 0; ni < 4; ++ni)
          acc[mi][ni] = __builtin_amdgcn_mfma_f32_16x16x32_bf16(af[mi], bfr[ni], acc[mi][ni], 0, 0, 0);
    }
    __syncthreads();
  }

#pragma unroll
  for (int mi = 0; mi < 4; ++mi) {
    int rb = wr*64 + mi*16 + l16*4;
#pragma unroll
    for (int ni = 0; ni < 4; ++ni) {
      int col = col0 + wc*64 + ni*16 + l15;
      float bv = bias[col];
#pragma unroll
      for (int jj = 0; jj < 4; ++jj)
        Cf[(row0 + rb + jj)*512 + col] = acc[mi][ni][jj] + bv;
    }
  }
}

// ---------------------------------------------------------------------------
extern "C" void kernel_launch(void* const* d_in, const int* in_sizes, int n_in,
                              void* d_out, int out_size, void* d_ws, size_t ws_size,
                              hipStream_t stream)
{
  const float* x  = (const float*)d_in[0];
  const float* y  = (const float*)d_in[1];
  const float* Wq = (const float*)d_in[2];
  const float* bq = (const float*)d_in[3];
  const float* Wk = (const float*)d_in[4];
  const float* bk = (const float*)d_in[5];
  const float* Wv = (const float*)d_in[6];
  const float* bv = (const float*)d_in[7];
  const float* Wp = (const float*)d_in[8];
  const float* bp = (const float*)d_in[9];
  float* out = (float*)d_out;
  char* ws = (char*)d_ws;

  const size_t SZ_BF = (size_t)M_ * C_ * 2;  // 32 MB bf16
  const size_t WCC   = (size_t)C_ * C_;      // 262144

  unsigned short* yb   = (unsigned short*)(ws);            // 3 terms, 96 MB
  unsigned short* qb   = (unsigned short*)(ws + 3*SZ_BF);
  unsigned short* kb   = (unsigned short*)(ws + 4*SZ_BF);  // partials, then out_pre
  unsigned short* wb   = (unsigned short*)(ws + 5*SZ_BF);  // 8*C*C bf16
  unsigned short* wq_b = wb;
  unsigned short* wk_b = wb + WCC;          // [3][512][512]
  unsigned short* wv_b = wb + 4*WCC;
  unsigned short* wp_b = wb + 7*WCC;
  float* ctxT = (float*)(wb + 8*WCC);
  float* kc   = ctxT + (size_t)3*64*64*64;

  float* part  = (float*)kb;                       // 192*8*4096*4 = 25.2 MB
  float* kcpar = part + (size_t)192*8*4096;        // 192*16*64*4  = 786 KB

  cvt_weights<<<dim3(128, 4), 256, 0, stream>>>(Wq, Wk, Wv, Wp, wb);

  // q-GEMM interleaved with y-cvt (role = blockIdx.x & 1)
  qcvt_kernel<<<2048, 256, 0, stream>>>(x, wq_b, bq, qb, y, yb);

  kvctx_kernel<<<dim3(512, 1, 3), 256, 0, stream>>>(
      yb, wk_b, wv_b, bk, bv, part, kcpar);
  ctx_reduce<<<192, 256, 0, stream>>>(part, kcpar, ctxT, kc);

  combine2<<<dim3(32, 64), 256, 0, stream>>>(qb, ctxT, kc, kb);
  gemm_final<<<dim3(M_/128, 4), 256, 0, stream>>>(kb, wp_b, bp, out);
}

// Round 19
// 363.531 us; speedup vs baseline: 1.0353x; 1.0353x over previous
//
#include <hip/hip_runtime.h>

// LinearCrossAttention: B=8, N=T=4096, C=512, H=8, d=64, 3 terms.
// R19 = R16 (best measured: 363.9 us). q-GEMM merged into kvctx launch via
// blockIdx.z; weights+y conversions in one launch; partials (no atomics);
// fused softmax epilogues; XOR-swizzled LDS staging everywhere.

#define B_  8
#define N_  4096
#define C_  512
#define T_  4096
#define H_  8
#define M_  (B_*N_)   // 32768

typedef __bf16 bf16_8 __attribute__((ext_vector_type(8)));
typedef __bf16 bf16_4 __attribute__((ext_vector_type(4)));
typedef float  f32_4  __attribute__((ext_vector_type(4)));

__device__ __forceinline__ unsigned short f2bf(float f) {
  unsigned u = __float_as_uint(f);
  unsigned r = 0x7FFFu + ((u >> 16) & 1u);
  return (unsigned short)((u + r) >> 16);
}

__device__ __forceinline__ void gload16(const void* g, void* l) {
  __builtin_amdgcn_global_load_lds(
      (const __attribute__((address_space(1))) unsigned int*)g,
      (__attribute__((address_space(3))) unsigned int*)l, 16, 0, 0);
}

__device__ __forceinline__ bf16_8 cvt8(float4 a, float4 b) {
  bf16_8 v;
  v[0]=(__bf16)a.x; v[1]=(__bf16)a.y; v[2]=(__bf16)a.z; v[3]=(__bf16)a.w;
  v[4]=(__bf16)b.x; v[5]=(__bf16)b.y; v[6]=(__bf16)b.z; v[7]=(__bf16)b.w;
  return v;
}

// ---------------- all conversions (weights + y) in one launch ---------------
__global__ __launch_bounds__(256) void cvt_all(
    const float* __restrict__ Wq, const float* __restrict__ Wk,
    const float* __restrict__ Wv, const float* __restrict__ Wp,
    const float* __restrict__ y,
    unsigned short* __restrict__ wb,   // [8*C*C] : Wq | Wk(3) | Wv(3) | Wp
    unsigned short* __restrict__ yb)
{
  const size_t WCC = (size_t)C_*C_;
  const float* src; unsigned short* dst; long n4;
  switch (blockIdx.y) {
    case 0: src = Wq; dst = wb;         n4 = WCC/4;          break;
    case 1: src = Wk; dst = wb + WCC;   n4 = 3*WCC/4;        break;
    case 2: src = Wv; dst = wb + 4*WCC; n4 = 3*WCC/4;        break;
    case 3: src = Wp; dst = wb + 7*WCC; n4 = WCC/4;          break;
    default: src = y; dst = yb;         n4 = (long)3*M_*C_/4; break;
  }
  long i = (long)blockIdx.x * blockDim.x + threadIdx.x;
  long stride = (long)gridDim.x * blockDim.x;
  for (; i < n4; i += stride) {
    float4 v = ((const float4*)src)[i];
    ushort4 o;
    o.x = f2bf(v.x); o.y = f2bf(v.y); o.z = f2bf(v.z); o.w = f2bf(v.w);
    ((ushort4*)dst)[i] = o;
  }
}

// ---------------- final GEMM (bf16 A), 128x128, BK=64 dbuf ------------------
__global__ __launch_bounds__(256, 2) void gemm_final(
    const unsigned short* __restrict__ A,    // [M][512] bf16
    const unsigned short* __restrict__ Bw,   // [512][512] bf16
    const float* __restrict__ bias,
    float* __restrict__ Cf)
{
  __shared__ char smem[65536];
  const int tid = threadIdx.x, lane = tid & 63, wid = tid >> 6;
  const int wr = wid >> 1, wc = wid & 1;
  const int l15 = lane & 15, l16 = lane >> 4;
  const size_t row0 = (size_t)blockIdx.x * 128;
  const int col0 = blockIdx.y * 128;

  f32_4 acc[4][4] = {};

  auto stage = [&](int k0, int bsel) {
#pragma unroll
    for (int j = 0; j < 4; ++j) {
      int cc = j*256 + tid, row = cc >> 3, s = cc & 7;
      gload16(A + (row0 + row)*512 + k0 + ((s ^ (row & 7)) << 3),
              smem + bsel*16384 + (size_t)(j*256 + wid*64)*16);
      gload16(Bw + (size_t)(col0 + row)*512 + k0 + ((s ^ (row & 7)) << 3),
              smem + 32768 + bsel*16384 + (size_t)(j*256 + wid*64)*16);
    }
  };

  stage(0, 0);
  __syncthreads();
  for (int t = 0; t < 8; ++t) {
    int cur = t & 1;
    if (t < 7) stage((t+1)*64, cur ^ 1);
    const unsigned short* sA = (const unsigned short*)(smem + cur*16384);
    const unsigned short* sB = (const unsigned short*)(smem + 32768 + cur*16384);
#pragma unroll
    for (int kk = 0; kk < 64; kk += 32) {
      bf16_8 af[4], bfr[4];
#pragma unroll
      for (int mi = 0; mi < 4; ++mi) {
        int r = wr*64 + mi*16 + l15;
        int ch = (kk >> 3) + l16;
        af[mi] = *(const bf16_8*)&sA[r*64 + ((ch ^ (r & 7)) << 3)];
      }
#pragma unroll
      for (int ni = 0; ni < 4; ++ni) {
        int r = wc*64 + ni*16 + l15;
        int ch = (kk >> 3) + l16;
        bfr[ni] = *(const bf16_8*)&sB[r*64 + ((ch ^ (r & 7)) << 3)];
      }
#pragma unroll
      for (int mi = 0; mi < 4; ++mi)
#pragma unroll
        for (int ni = 0; ni < 4; ++ni)
          acc[mi][ni] = __builtin_amdgcn_mfma_f32_16x16x32_bf16(af[mi], bfr[ni], acc[mi][ni], 0, 0, 0);
    }
    __syncthreads();
  }

#pragma unroll
  for (int mi = 0; mi < 4; ++mi) {
    int rb = wr*64 + mi*16 + l16*4;
#pragma unroll
    for (int ni = 0; ni < 4; ++ni) {
      int col = col0 + wc*64 + ni*16 + l15;
      float bv = bias[col];
#pragma unroll
      for (int jj = 0; jj < 4; ++jj)
        Cf[(row0 + rb + jj)*512 + col] = acc[mi][ni][jj] + bv;
    }
  }
}

// ---------------- mega: q-GEMM (z<2) + kvctx (z>=2) -------------------------
// grid (512, 1, 5). z in {0,1}: q-gemm block qidx = z*512+bx (row=qidx&255,
// col=qidx>>8). z in {2,3,4}: kvctx term i=z-2, gx=bx.
__global__ __launch_bounds__(256, 2) void mega_kernel(
    const float* __restrict__ xf,
    const unsigned short* __restrict__ wq_b, const float* __restrict__ bq,
    unsigned short* __restrict__ qb,
    const unsigned short* __restrict__ yb_all,
    const unsigned short* __restrict__ wk_all,
    const unsigned short* __restrict__ wv_all,
    const float* __restrict__ bk_all, const float* __restrict__ bv_all,
    float* __restrict__ part, float* __restrict__ kcp)
{
  __shared__ char smem[65536];
  const int tid = threadIdx.x, lane = tid & 63, wid = tid >> 6;
  const int wr = wid >> 1, wc = wid & 1;
  const int l15 = lane & 15, l16 = lane >> 4;
  const int z = blockIdx.z;

  if (z < 2) {
    // ======== q-GEMM: qb = softmax(x @ Wq^T + bq), A = x f32 ========
    const int qidx = z*512 + blockIdx.x;
    const size_t row0 = (size_t)(qidx & 255) * 128;
    const int col0 = (qidx >> 8) * 128;

    f32_4 acc[4][4] = {};
    float4 ra[4][2];

    auto load_a = [&](int k0) {
#pragma unroll
      for (int j = 0; j < 4; ++j) {
        int cc = j*256 + tid, row = cc >> 3, s = cc & 7;
        const float* src = xf + (row0 + row)*512 + k0 + s*8;
        ra[j][0] = *(const float4*)src;
        ra[j][1] = *(const float4*)(src + 4);
      }
    };
    auto write_a = [&](int bsel) {
      unsigned short* dst = (unsigned short*)smem;
#pragma unroll
      for (int j = 0; j < 4; ++j) {
        int cc = j*256 + tid, row = cc >> 3, s = cc & 7;
        *(bf16_8*)&dst[bsel*8192 + row*64 + ((s ^ (row & 7)) << 3)] = cvt8(ra[j][0], ra[j][1]);
      }
    };
    auto stage_b = [&](int k0, int bsel) {
#pragma unroll
      for (int j = 0; j < 4; ++j) {
        int cc = j*256 + tid, row = cc >> 3, s = cc & 7;
        gload16(wq_b + (size_t)(col0 + row)*512 + k0 + ((s ^ (row & 7)) << 3),
                smem + 32768 + bsel*16384 + (size_t)(j*256 + wid*64)*16);
      }
    };

    load_a(0); stage_b(0, 0); write_a(0);
    __syncthreads();
    for (int t = 0; t < 8; ++t) {
      int cur = t & 1;
      if (t < 7) { load_a((t+1)*64); stage_b((t+1)*64, cur ^ 1); }
      const unsigned short* sA = (const unsigned short*)(smem + cur*16384);
      const unsigned short* sB = (const unsigned short*)(smem + 32768 + cur*16384);
#pragma unroll
      for (int kk = 0; kk < 64; kk += 32) {
        bf16_8 af[4], bfr[4];
#pragma unroll
        for (int mi = 0; mi < 4; ++mi) {
          int r = wr*64 + mi*16 + l15;
          int ch = (kk >> 3) + l16;
          af[mi] = *(const bf16_8*)&sA[r*64 + ((ch ^ (r & 7)) << 3)];
        }
#pragma unroll
        for (int ni = 0; ni < 4; ++ni) {
          int r = wc*64 + ni*16 + l15;
          int ch = (kk >> 3) + l16;
          bfr[ni] = *(const bf16_8*)&sB[r*64 + ((ch ^ (r & 7)) << 3)];
        }
#pragma unroll
        for (int mi = 0; mi < 4; ++mi)
#pragma unroll
          for (int ni = 0; ni < 4; ++ni)
            acc[mi][ni] = __builtin_amdgcn_mfma_f32_16x16x32_bf16(af[mi], bfr[ni], acc[mi][ni], 0, 0, 0);
      }
      if (t < 7) write_a(cur ^ 1);
      __syncthreads();
    }

    float bvv[4];
#pragma unroll
    for (int ni = 0; ni < 4; ++ni) bvv[ni] = bq[col0 + wc*64 + ni*16 + l15];
    unsigned short* sE = (unsigned short*)smem;   // 128 x pitch 136
#pragma unroll
    for (int mi = 0; mi < 4; ++mi) {
#pragma unroll
      for (int jj = 0; jj < 4; ++jj) {
        float x[4];
        float s = 0.f;
#pragma unroll
        for (int ni = 0; ni < 4; ++ni) {
          x[ni] = __expf(acc[mi][ni][jj] + bvv[ni]);   // bounded: no max-sub
          s += x[ni];
        }
#pragma unroll
        for (int o = 8; o; o >>= 1) s += __shfl_xor(s, o);
        float inv = 1.0f / s;
        int r = wr*64 + mi*16 + l16*4 + jj;
#pragma unroll
        for (int ni = 0; ni < 4; ++ni) {
          __bf16 h = (__bf16)(x[ni] * inv);
          sE[r*136 + wc*64 + ni*16 + l15] = *(unsigned short*)&h;
        }
      }
    }
    __syncthreads();
    int r = tid >> 1, seg = tid & 1;
    unsigned short* orow = qb + (row0 + r)*512 + col0 + seg*64;
#pragma unroll
    for (int u = 0; u < 8; ++u)
      *(uint4*)(orow + u*8) = *(const uint4*)&sE[r*136 + seg*64 + u*8];
    return;
  }

  // ======== kvctx: term i = z-2 (BK=64) ========
  unsigned short* sKT = (unsigned short*)smem;             // 64*136*2 = 17408
  unsigned short* sVT = (unsigned short*)(smem + 17408);

  const int gx = blockIdx.x, i = z - 2;
  const int h = gx >> 6, bx = gx & 63;       // same bx (y slab) -> same XCD
  const int b = bx >> 3, sub = bx & 7;
  const int bh = b*8 + h;

  const unsigned short* yb = yb_all + (size_t)i*M_*512;
  const unsigned short* Wk_b = wk_all + (size_t)i*512*512 + (size_t)h*64*512;
  const unsigned short* Wv_b = wv_all + (size_t)i*512*512 + (size_t)h*64*512;
  const float* bk = bk_all + i*512 + h*64;
  const float* bv = bv_all + i*512 + h*64;

  f32_4 cacc[2][2] = {};
  float kcp_r[4] = {0.f, 0.f, 0.f, 0.f};

  for (int chunk = 0; chunk < 4; ++chunk) {
    const size_t row0 = (size_t)bx*512 + chunk*128;
    f32_4 acc[4][4] = {};

    auto stage = [&](int k0, int bsel) {
#pragma unroll
      for (int j = 0; j < 4; ++j) {
        int cc = j*256 + tid, row = cc >> 3, s = cc & 7;
        gload16(yb + (row0 + row)*512 + k0 + ((s ^ (row & 7)) << 3),
                smem + bsel*16384 + (size_t)(j*256 + wid*64)*16);
        const unsigned short* wsrc = (j < 2)
            ? Wk_b + (size_t)row*512
            : Wv_b + (size_t)(row - 64)*512;
        gload16(wsrc + k0 + ((s ^ (row & 7)) << 3),
                smem + 32768 + bsel*16384 + (size_t)(j*256 + wid*64)*16);
      }
    };

    stage(0, 0);
    __syncthreads();
    for (int t = 0; t < 8; ++t) {
      int cur = t & 1;
      if (t < 7) stage((t+1)*64, cur ^ 1);
      const unsigned short* sA = (const unsigned short*)(smem + cur*16384);
      const unsigned short* sB = (const unsigned short*)(smem + 32768 + cur*16384);
#pragma unroll
      for (int kk = 0; kk < 64; kk += 32) {
        bf16_8 af[4], bfr[4];
#pragma unroll
        for (int mi = 0; mi < 4; ++mi) {
          int r = wr*64 + mi*16 + l15;
          int ch = (kk >> 3) + l16;
          af[mi] = *(const bf16_8*)&sA[r*64 + ((ch ^ (r & 7)) << 3)];
        }
#pragma unroll
        for (int ni = 0; ni < 4; ++ni) {
          int r = wc*64 + ni*16 + l15;
          int ch = (kk >> 3) + l16;
          bfr[ni] = *(const bf16_8*)&sB[r*64 + ((ch ^ (r & 7)) << 3)];
        }
#pragma unroll
        for (int mi = 0; mi < 4; ++mi)
#pragma unroll
          for (int ni = 0; ni < 4; ++ni)
            acc[mi][ni] = __builtin_amdgcn_mfma_f32_16x16x32_bf16(af[mi], bfr[ni], acc[mi][ni], 0, 0, 0);
      }
      __syncthreads();
    }

    if (wc == 0) {
      float bkv[4];
#pragma unroll
      for (int ni = 0; ni < 4; ++ni) bkv[ni] = bk[ni*16 + l15];
#pragma unroll
      for (int mi = 0; mi < 4; ++mi) {
        float kv[4][4];   // [jj][ni]
#pragma unroll
        for (int jj = 0; jj < 4; ++jj) {
          float s = 0.f;
#pragma unroll
          for (int ni = 0; ni < 4; ++ni) {
            kv[jj][ni] = __expf(acc[mi][ni][jj] + bkv[ni]);
            s += kv[jj][ni];
          }
#pragma unroll
          for (int o = 8; o; o >>= 1) s += __shfl_xor(s, o);
          float inv = 1.0f / s;
#pragma unroll
          for (int ni = 0; ni < 4; ++ni) kv[jj][ni] *= inv;
        }
        int r0 = wr*64 + mi*16 + l16*4;
#pragma unroll
        for (int ni = 0; ni < 4; ++ni) {
          kcp_r[ni] += (kv[0][ni] + kv[1][ni]) + (kv[2][ni] + kv[3][ni]);
          bf16_4 p;
#pragma unroll
          for (int jj = 0; jj < 4; ++jj) p[jj] = (__bf16)kv[jj][ni];
          *(bf16_4*)&sKT[(ni*16 + l15)*136 + r0] = p;
        }
      }
    } else {
      float bvv[4];
#pragma unroll
      for (int ni = 0; ni < 4; ++ni) bvv[ni] = bv[ni*16 + l15];
#pragma unroll
      for (int mi = 0; mi < 4; ++mi) {
        int r0 = wr*64 + mi*16 + l16*4;
#pragma unroll
        for (int ni = 0; ni < 4; ++ni) {
          bf16_4 p;
#pragma unroll
          for (int jj = 0; jj < 4; ++jj) p[jj] = (__bf16)(acc[mi][ni][jj] + bvv[ni]);
          *(bf16_4*)&sVT[(ni*16 + l15)*136 + r0] = p;
        }
      }
    }
    __syncthreads();

#pragma unroll
    for (int ks = 0; ks < 4; ++ks) {
      bf16_8 a2[2], b2[2];
#pragma unroll
      for (int mi = 0; mi < 2; ++mi)
        a2[mi] = *(const bf16_8*)&sKT[(wr*32 + mi*16 + l15)*136 + ks*32 + l16*8];
#pragma unroll
      for (int ni = 0; ni < 2; ++ni)
        b2[ni] = *(const bf16_8*)&sVT[(wc*32 + ni*16 + l15)*136 + ks*32 + l16*8];
#pragma unroll
      for (int mi = 0; mi < 2; ++mi)
#pragma unroll
        for (int ni = 0; ni < 2; ++ni)
          cacc[mi][ni] = __builtin_amdgcn_mfma_f32_16x16x32_bf16(a2[mi], b2[ni], cacc[mi][ni], 0, 0, 0);
    }
    __syncthreads();
  }

  const size_t slot = (size_t)(i*64 + bh)*8 + sub;
  if (wc == 0) {
#pragma unroll
    for (int ni = 0; ni < 4; ++ni) {
      float s = kcp_r[ni];
      s += __shfl_xor(s, 16);
      s += __shfl_xor(s, 32);
      if (l16 == 0) kcp[(slot*2 + wr)*64 + ni*16 + l15] = s;
    }
  }
  float* pb = part + slot*4096;
#pragma unroll
  for (int mi = 0; mi < 2; ++mi)
#pragma unroll
    for (int ni = 0; ni < 2; ++ni) {
      int e0 = wr*32 + mi*16 + l16*4;
      int dv = wc*32 + ni*16 + l15;
      *(f32_4*)&pb[dv*64 + e0] = cacc[mi][ni];
    }
}

// ---------------- reduce partials -> ctxT, kc -------------------------------
__global__ __launch_bounds__(256) void ctx_reduce(
    const float* __restrict__ part,   // [192][8][4096]
    const float* __restrict__ kcp,    // [192][8][2][64]
    float* __restrict__ ctxT,         // [192][4096]
    float* __restrict__ kc)           // [192][64]
{
  int g = blockIdx.x;
  const float* p = part + (size_t)g*8*4096;
  float* o = ctxT + (size_t)g*4096;
#pragma unroll
  for (int jj = 0; jj < 4; ++jj) {
    int j = (jj*256 + threadIdx.x)*4;
    f32_4 s = {};
#pragma unroll
    for (int r = 0; r < 8; ++r) {
      f32_4 v = *(const f32_4*)&p[(size_t)r*4096 + j];
      s[0] += v[0]; s[1] += v[1]; s[2] += v[2]; s[3] += v[3];
    }
    *(f32_4*)&o[j] = s;
  }
  if (threadIdx.x < 64) {
    const float* pk = kcp + (size_t)g*16*64;
    float s = 0.f;
#pragma unroll
    for (int r = 0; r < 16; ++r) s += pk[r*64 + threadIdx.x];
    kc[(size_t)g*64 + threadIdx.x] = s;
  }
}

// ---------------- combine (MFMA): out = q + sum_i (q@ctx_i)/(q.kc_i) --------
__global__ __launch_bounds__(256) void combine2(
    const unsigned short* __restrict__ qb,
    const float* __restrict__ ctxT,          // [3][64bh][64dv][64e]
    const float* __restrict__ kc,            // [3][64bh][64e]
    unsigned short* __restrict__ outp)
{
  __shared__ unsigned short sQ[128*64];
  __shared__ unsigned short sB[208*64];
  __shared__ float sS[128*3];
  const int tid = threadIdx.x, lane = tid & 63, wid = tid >> 6;
  const int l15 = lane & 15, l16 = lane >> 4;
  const int bh = blockIdx.y, b = bh >> 3, h = bh & 7;
  const int n0 = blockIdx.x * 128;
  const size_t qbase = ((size_t)b*N_ + n0)*C_ + h*64;

#pragma unroll
  for (int j = 0; j < 4; ++j) {
    int c = j*256 + tid;
    int row = c >> 3, c8 = c & 7;
    gload16(qb + qbase + (size_t)row*C_ + c8*8, sQ + (size_t)(j*256 + wid*64)*8);
  }
  for (int f = tid; f < 208*64; f += 256) {
    int col = f >> 6, e = f & 63;
    float val = 0.f;
    if (col < 192)
      val = ctxT[(((size_t)(col >> 6)*64 + bh)*64 + (col & 63))*64 + e];
    else if (col < 195)
      val = kc[((size_t)(col - 192)*64 + bh)*64 + e];
    __bf16 hv = (__bf16)val;
    sB[col*64 + e] = *(unsigned short*)&hv;
  }
  __syncthreads();

  f32_4 acc[2][13] = {};
#pragma unroll
  for (int ks = 0; ks < 2; ++ks) {
    bf16_8 af[2];
#pragma unroll
    for (int mi = 0; mi < 2; ++mi)
      af[mi] = *(const bf16_8*)&sQ[(wid*32 + mi*16 + l15)*64 + ks*32 + l16*8];
#pragma unroll
    for (int ni = 0; ni < 13; ++ni) {
      bf16_8 bfr = *(const bf16_8*)&sB[(ni*16 + l15)*64 + ks*32 + l16*8];
#pragma unroll
      for (int mi = 0; mi < 2; ++mi)
        acc[mi][ni] = __builtin_amdgcn_mfma_f32_16x16x32_bf16(af[mi], bfr, acc[mi][ni], 0, 0, 0);
    }
  }

  if (l15 < 3) {
#pragma unroll
    for (int mi = 0; mi < 2; ++mi)
#pragma unroll
      for (int jj = 0; jj < 4; ++jj)
        sS[(wid*32 + mi*16 + l16*4 + jj)*3 + l15] = acc[mi][12][jj];
  }
  __syncthreads();

#pragma unroll
  for (int mi = 0; mi < 2; ++mi) {
#pragma unroll
    for (int jj = 0; jj < 4; ++jj) {
      int r = wid*32 + mi*16 + l16*4 + jj;
      float inv[3];
#pragma unroll
      for (int i = 0; i < 3; ++i) inv[i] = 1.0f / sS[r*3 + i];
#pragma unroll
      for (int ni = 0; ni < 4; ++ni) {
        int dv = ni*16 + l15;
        unsigned short qh = sQ[r*64 + dv];
        float val = __uint_as_float(((unsigned)qh) << 16);
#pragma unroll
        for (int i = 0; i < 3; ++i) val += acc[mi][i*4 + ni][jj] * inv[i];
        __bf16 hv = (__bf16)val;
        outp[qbase + (size_t)r*C_ + dv] = *(unsigned short*)&hv;
      }
    }
  }
}

// ---------------------------------------------------------------------------
extern "C" void kernel_launch(void* const* d_in, const int* in_sizes, int n_in,
                              void* d_out, int out_size, void* d_ws, size_t ws_size,
                              hipStream_t stream)
{
  const float* x  = (const float*)d_in[0];
  const float* y  = (const float*)d_in[1];
  const float* Wq = (const float*)d_in[2];
  const float* bq = (const float*)d_in[3];
  const float* Wk = (const float*)d_in[4];
  const float* bk = (const float*)d_in[5];
  const float* Wv = (const float*)d_in[6];
  const float* bv = (const float*)d_in[7];
  const float* Wp = (const float*)d_in[8];
  const float* bp = (const float*)d_in[9];
  float* out = (float*)d_out;
  char* ws = (char*)d_ws;

  const size_t SZ_BF = (size_t)M_ * C_ * 2;  // 32 MB bf16
  const size_t WCC   = (size_t)C_ * C_;      // 262144

  unsigned short* yb   = (unsigned short*)(ws);            // 3 terms, 96 MB
  unsigned short* qb   = (unsigned short*)(ws + 3*SZ_BF);
  unsigned short* kb   = (unsigned short*)(ws + 4*SZ_BF);  // partials, then out_pre
  unsigned short* wb   = (unsigned short*)(ws + 5*SZ_BF);  // 8*C*C bf16
  unsigned short* wq_b = wb;
  unsigned short* wk_b = wb + WCC;          // [3][512][512]
  unsigned short* wv_b = wb + 4*WCC;
  unsigned short* wp_b = wb + 7*WCC;
  float* ctxT = (float*)(wb + 8*WCC);
  float* kc   = ctxT + (size_t)3*64*64*64;

  float* part  = (float*)kb;                       // 192*8*4096*4 = 25.2 MB
  float* kcpar = part + (size_t)192*8*4096;        // 192*16*64*4  = 786 KB

  cvt_all<<<dim3(2048, 5), 256, 0, stream>>>(Wq, Wk, Wv, Wp, y, wb, yb);

  // q-GEMM + all 3 kvctx terms in one launch
  mega_kernel<<<dim3(512, 1, 5), 256, 0, stream>>>(
      x, wq_b, bq, qb, yb, wk_b, wv_b, bk, bv, part, kcpar);
  ctx_reduce<<<192, 256, 0, stream>>>(part, kcpar, ctxT, kc);

  combine2<<<dim3(32, 64), 256, 0, stream>>>(qb, ctxT, kc, kb);
  gemm_final<<<dim3(M_/128, 4), 256, 0, stream>>>(kb, wp_b, bp, out);
}